// Round 1
// baseline (4303.772 us; speedup 1.0000x reference)
//
#include <hip/hip_runtime.h>
#include <hip/hip_bf16.h>

#define CC 64

// ---------------------------------------------------------------------------
// Prep: transpose Wm1 (8x64 -> 64x8) and Wm3 (64x320 -> 320x64) into ws so the
// per-edge uniform dot products read contiguous scalar memory.
// ---------------------------------------------------------------------------
__global__ __launch_bounds__(256) void prep_kernel(
    const float* __restrict__ Wm1, const float* __restrict__ Wm3,
    float* __restrict__ Wm1T, float* __restrict__ Wm3T)
{
    int idx = blockIdx.x * 256 + threadIdx.x;
    if (idx < 512) {
        int j = idx >> 3, n = idx & 7;           // Wm1T[j*8+n] = Wm1[n][j]
        Wm1T[idx] = Wm1[n * 64 + j];
    } else if (idx < 512 + 20480) {
        int t = idx - 512;
        int o = t >> 6, k = t & 63;              // Wm3T[o*64+k] = Wm3[k][o]
        Wm3T[t] = Wm3[k * 320 + o];
    }
}

// ---------------------------------------------------------------------------
// Node up-projection: u[n] = [u0(64) | u1x(64) | u1y(64) | u1z(64)]
// u0 = x0 @ W0_up ; u1[:,:,i] = x1[:,:,i] @ W1_up
// node_feats row: [x0(64), x1 interleaved c*3+i (192)]
// ---------------------------------------------------------------------------
__global__ __launch_bounds__(256) void node_up_kernel(
    const float* __restrict__ node_feats, const float* __restrict__ W0_up,
    const float* __restrict__ W1_up, float* __restrict__ u)
{
    int n = blockIdx.x;
    int t = threadIdx.x;
    const float* nf = node_feats + (size_t)n * 256;
    float f = 0.f;
    if (t < 64) {
        #pragma unroll 8
        for (int c = 0; c < 64; ++c) f += nf[c] * W0_up[c * 64 + t];
        u[(size_t)n * 256 + t] = f;
    } else {
        int i = (t - 64) >> 6;   // component, uniform per wave
        int d = t & 63;
        #pragma unroll 8
        for (int c = 0; c < 64; ++c) f += nf[64 + c * 3 + i] * W1_up[c * 64 + d];
        u[(size_t)n * 256 + 64 + i * 64 + d] = f;
    }
}

// ---------------------------------------------------------------------------
// Edge kernel: one THREAD per edge. All weight accesses are wave-uniform ->
// scalar loads; activations live in VGPRs (h2[64], statically indexed).
// Scatter via fp32 atomics into acc[n] = [a0(64) | a1x | a1y | a1z].
// ---------------------------------------------------------------------------
__global__ __launch_bounds__(256) void edge_kernel(
    const float* __restrict__ vectors, const int* __restrict__ senders,
    const int* __restrict__ receivers, const float* __restrict__ u,
    const float* __restrict__ Wm1T, const float* __restrict__ Wm2,
    const float* __restrict__ Wm3T, float* __restrict__ acc, int E)
{
    int e = blockIdx.x * 256 + threadIdx.x;
    if (e >= E) return;

    float vx = vectors[3 * (size_t)e + 0];
    float vy = vectors[3 * (size_t)e + 1];
    float vz = vectors[3 * (size_t)e + 2];
    float r = sqrtf(vx * vx + vy * vy + vz * vz);
    if (r == 0.0f) return;                 // wmix==0 -> all messages zero
    float inv_r = 1.0f / r;
    float Yx = vx * inv_r, Yy = vy * inv_r, Yz = vz * inv_r;

    // radial basis: sqrt(2/5)*sin((b+1)*pi*r/5)/r
    float basis[8];
    const float ang = r * 0.6283185307179586f;   // pi/5
    #pragma unroll
    for (int b = 0; b < 8; ++b)
        basis[b] = 0.6324555320336759f * __sinf((float)(b + 1) * ang) * inv_r;

    // h2 = silu(silu(basis@Wm1) @ Wm2)
    float h2[64];
    #pragma unroll
    for (int j = 0; j < 64; ++j) h2[j] = 0.f;
    for (int k = 0; k < 64; ++k) {
        float a = 0.f;
        #pragma unroll
        for (int b = 0; b < 8; ++b) a += basis[b] * Wm1T[k * 8 + b];
        float h1k = a / (1.f + __expf(-a));
        const float* w2r = Wm2 + k * 64;
        #pragma unroll
        for (int j = 0; j < 64; ++j) h2[j] += h1k * w2r[j];
    }
    #pragma unroll
    for (int j = 0; j < 64; ++j) h2[j] = h2[j] / (1.f + __expf(-h2[j]));

    int s = senders[e], rc = receivers[e];
    const float* us = u + (size_t)s * 256;
    float* ar = acc + (size_t)rc * 256;

    for (int d = 0; d < 64; ++d) {
        // sender features (scattered, L3-resident)
        float m0v = us[d];
        float m1x = us[64 + d], m1y = us[128 + d], m1z = us[192 + d];

        // wmix[:,d] for the 5 paths: uniform contiguous scalar dot products
        const float* p0 = Wm3T + (size_t)(0 * 64 + d) * 64;
        const float* p1 = Wm3T + (size_t)(1 * 64 + d) * 64;
        const float* p2 = Wm3T + (size_t)(2 * 64 + d) * 64;
        const float* p3 = Wm3T + (size_t)(3 * 64 + d) * 64;
        const float* p4 = Wm3T + (size_t)(4 * 64 + d) * 64;
        float w00 = 0.f, w01 = 0.f, w10 = 0.f, w11d = 0.f, w11c = 0.f;
        #pragma unroll
        for (int k = 0; k < 64; ++k) {
            float hk = h2[k];
            w00  += hk * p0[k];
            w01  += hk * p1[k];
            w10  += hk * p2[k];
            w11d += hk * p3[k];
            w11c += hk * p4[k];
        }

        float dotv = m1x * Yx + m1y * Yy + m1z * Yz;
        float cx = m1y * Yz - m1z * Yy;
        float cy = m1z * Yx - m1x * Yz;
        float cz = m1x * Yy - m1y * Yx;

        float msg0 = w00 * m0v + w11d * dotv;
        float wm = w01 * m0v;

        atomicAdd(&ar[d], msg0);
        atomicAdd(&ar[64 + d],  wm * Yx + w10 * m1x + w11c * cx);
        atomicAdd(&ar[128 + d], wm * Yy + w10 * m1y + w11c * cy);
        atomicAdd(&ar[192 + d], wm * Yz + w10 * m1z + w11c * cz);
    }
}

// ---------------------------------------------------------------------------
// Node epilogue: f0 = 0.25*a0@Wd0 + x0@Ws0[sp]; f1 = 0.25*a1@Wd1 + x1@Ws1[sp]
// out[n] = [silu(f0[:64]) | (f1 * silu(f0[64:]))  as (c,i) -> 64 + c*3 + i]
// ---------------------------------------------------------------------------
__global__ __launch_bounds__(256) void node_out_kernel(
    const float* __restrict__ acc, const float* __restrict__ node_feats,
    const int* __restrict__ node_specie,
    const float* __restrict__ Wd0, const float* __restrict__ Wd1,
    const float* __restrict__ Ws0, const float* __restrict__ Ws1,
    float* __restrict__ out)
{
    int n = blockIdx.x;
    int t = threadIdx.x;
    __shared__ float gates[64];
    int sp = node_specie[n];
    const float* accn = acc + (size_t)n * 256;
    const float* nf = node_feats + (size_t)n * 256;

    if (t < 128) {
        const float* ws0 = Ws0 + (size_t)sp * 64 * 128;
        float f = 0.f;
        #pragma unroll 8
        for (int c = 0; c < 64; ++c) {
            f += (0.25f * accn[c]) * Wd0[c * 128 + t];
            f += nf[c] * ws0[c * 128 + t];
        }
        float sv = f / (1.f + __expf(-f));
        if (t < 64) out[(size_t)n * 256 + t] = sv;   // scalars
        else        gates[t - 64] = sv;              // gates
    }
    __syncthreads();
    if (t < 192) {
        int i = t >> 6;       // component, uniform per wave
        int c2 = t & 63;
        const float* ws1 = Ws1 + (size_t)sp * 64 * 64;
        float f = 0.f;
        #pragma unroll 8
        for (int cc = 0; cc < 64; ++cc) {
            f += (0.25f * accn[64 + i * 64 + cc]) * Wd1[cc * 64 + c2];
            f += nf[64 + cc * 3 + i] * ws1[cc * 64 + c2];
        }
        out[(size_t)n * 256 + 64 + c2 * 3 + i] = f * gates[c2];
    }
}

// ---------------------------------------------------------------------------
extern "C" void kernel_launch(void* const* d_in, const int* in_sizes, int n_in,
                              void* d_out, int out_size, void* d_ws, size_t ws_size,
                              hipStream_t stream) {
    const float* vectors     = (const float*)d_in[0];
    const float* node_feats  = (const float*)d_in[1];
    const int*   node_specie = (const int*)d_in[2];
    const int*   senders     = (const int*)d_in[3];
    const int*   receivers   = (const int*)d_in[4];
    const float* W0_up       = (const float*)d_in[5];
    const float* W1_up       = (const float*)d_in[6];
    const float* Wm1         = (const float*)d_in[7];
    const float* Wm2         = (const float*)d_in[8];
    const float* Wm3         = (const float*)d_in[9];
    const float* Ws0         = (const float*)d_in[10];
    const float* Ws1         = (const float*)d_in[11];
    const float* Wd0         = (const float*)d_in[12];
    const float* Wd1         = (const float*)d_in[13];
    float* out = (float*)d_out;

    int E = in_sizes[0] / 3;
    int N = in_sizes[1] / 256;

    float* u    = (float*)d_ws;                    // N*256
    float* acc  = u + (size_t)N * 256;             // N*256
    float* Wm1T = acc + (size_t)N * 256;           // 512
    float* Wm3T = Wm1T + 512;                      // 20480

    hipMemsetAsync(acc, 0, (size_t)N * 256 * sizeof(float), stream);

    prep_kernel<<<82, 256, 0, stream>>>(Wm1, Wm3, Wm1T, Wm3T);
    node_up_kernel<<<N, 256, 0, stream>>>(node_feats, W0_up, W1_up, u);
    edge_kernel<<<(E + 255) / 256, 256, 0, stream>>>(
        vectors, senders, receivers, u, Wm1T, Wm2, Wm3T, acc, E);
    node_out_kernel<<<N, 256, 0, stream>>>(
        acc, node_feats, node_specie, Wd0, Wd1, Ws0, Ws1, out);
}

// Round 2
// 1021.178 us; speedup vs baseline: 4.2145x; 4.2145x over previous
//
#include <hip/hip_runtime.h>
#include <hip/hip_bf16.h>

#define EB 4   // edges per wave iteration

// ---------------------------------------------------------------------------
// Node up-projection: u[n] = [u0(64) | u1x(64) | u1y(64) | u1z(64)]
// ---------------------------------------------------------------------------
__global__ __launch_bounds__(256) void node_up_kernel(
    const float* __restrict__ node_feats, const float* __restrict__ W0_up,
    const float* __restrict__ W1_up, float* __restrict__ u)
{
    int n = blockIdx.x;
    int t = threadIdx.x;
    const float* nf = node_feats + (size_t)n * 256;
    float f = 0.f;
    if (t < 64) {
        #pragma unroll 8
        for (int c = 0; c < 64; ++c) f += nf[c] * W0_up[c * 64 + t];
        u[(size_t)n * 256 + t] = f;
    } else {
        int i = (t - 64) >> 6;   // component, uniform per wave
        int d = t & 63;
        #pragma unroll 8
        for (int c = 0; c < 64; ++c) f += nf[64 + c * 3 + i] * W1_up[c * 64 + d];
        u[(size_t)n * 256 + 64 + i * 64 + d] = f;
    }
}

// ---------------------------------------------------------------------------
// Edge kernel v2: one WAVE per EB edges, lane = channel.
//  - h1/h2 distributed across lanes, broadcast via per-wave LDS rows
//  - Wm1/Wm2 columns hoisted into registers (static indices only)
//  - Wm3 read coalesced from L2, amortized over EB edges
//  - coalesced u-gather + coalesced atomicAdd scatter
// ---------------------------------------------------------------------------
__global__ __launch_bounds__(256, 2) void edge_kernel(
    const float* __restrict__ vectors, const int* __restrict__ senders,
    const int* __restrict__ receivers, const float* __restrict__ u,
    const float* __restrict__ Wm1, const float* __restrict__ Wm2,
    const float* __restrict__ Wm3, float* __restrict__ acc, int E)
{
    __shared__ float ldsH1[4][EB][64];
    __shared__ float ldsH2[4][EB][64];

    const int lane = threadIdx.x & 63;
    const int wv   = threadIdx.x >> 6;
    const int gwave  = blockIdx.x * 4 + wv;
    const int nwaves = gridDim.x * 4;
    const int ngroups = (E + EB - 1) / EB;

    // hoisted per-lane weight columns (loaded once per wave lifetime)
    float wm1c[8], wm2c[64];
    #pragma unroll
    for (int b = 0; b < 8; ++b) wm1c[b] = Wm1[b * 64 + lane];
    #pragma unroll
    for (int k = 0; k < 64; ++k) wm2c[k] = Wm2[k * 64 + lane];

    for (int g = gwave; g < ngroups; g += nwaves) {
        const int e0 = g * EB;

        float Yx[EB], Yy[EB], Yz[EB];
        int   sidx[EB], ridx[EB];
        bool  val[EB];

        // ---- layer 1: basis -> h1 (lane = hidden channel) ----
        #pragma unroll
        for (int j = 0; j < EB; ++j) {
            const int e = e0 + j;
            bool v = (e < E);
            const int ee = v ? e : 0;
            float vx = vectors[3 * (size_t)ee + 0];
            float vy = vectors[3 * (size_t)ee + 1];
            float vz = vectors[3 * (size_t)ee + 2];
            float r = sqrtf(vx * vx + vy * vy + vz * vz);
            v = v && (r != 0.0f);
            float ir = v ? 1.0f / r : 0.0f;     // ir==0 -> basis=0 -> wmix=0
            Yx[j] = vx * ir; Yy[j] = vy * ir; Yz[j] = vz * ir;
            sidx[j] = v ? senders[ee]   : 0;
            ridx[j] = v ? receivers[ee] : 0;
            val[j] = v;

            float ang = r * 0.6283185307179586f;   // pi/5
            float a = 0.f;
            #pragma unroll
            for (int b = 0; b < 8; ++b) {
                float bs = 0.6324555320336759f * __sinf((float)(b + 1) * ang) * ir;
                a += bs * wm1c[b];
            }
            ldsH1[wv][j][lane] = a / (1.f + __expf(-a));
        }

        // ---- layer 2: h2[lane] = silu(sum_k h1[k] * Wm2[k][lane]) ----
        float h2a[EB];
        #pragma unroll
        for (int j = 0; j < EB; ++j) h2a[j] = 0.f;
        #pragma unroll
        for (int k = 0; k < 64; k += 4) {
            float hh[EB][4];
            #pragma unroll
            for (int j = 0; j < EB; ++j) {
                float4 t = *(const float4*)&ldsH1[wv][j][k];   // uniform -> broadcast
                hh[j][0] = t.x; hh[j][1] = t.y; hh[j][2] = t.z; hh[j][3] = t.w;
            }
            #pragma unroll
            for (int kk = 0; kk < 4; ++kk)
                #pragma unroll
                for (int j = 0; j < EB; ++j)
                    h2a[j] += hh[j][kk] * wm2c[k + kk];
        }
        #pragma unroll
        for (int j = 0; j < EB; ++j)
            ldsH2[wv][j][lane] = h2a[j] / (1.f + __expf(-h2a[j]));

        // ---- layer 3: wmix[p*64+lane] = sum_k h2[k] * Wm3[k][p*64+lane] ----
        float w00[EB], w01[EB], w10[EB], w11d[EB], w11c[EB];
        #pragma unroll
        for (int j = 0; j < EB; ++j) {
            w00[j] = 0.f; w01[j] = 0.f; w10[j] = 0.f; w11d[j] = 0.f; w11c[j] = 0.f;
        }
        #pragma unroll 2
        for (int k = 0; k < 64; k += 4) {
            float hh[EB][4];
            #pragma unroll
            for (int j = 0; j < EB; ++j) {
                float4 t = *(const float4*)&ldsH2[wv][j][k];   // uniform -> broadcast
                hh[j][0] = t.x; hh[j][1] = t.y; hh[j][2] = t.z; hh[j][3] = t.w;
            }
            #pragma unroll
            for (int kk = 0; kk < 4; ++kk) {
                const float* wrow = Wm3 + (size_t)(k + kk) * 320;
                float g0 = wrow[lane];
                float g1 = wrow[64 + lane];
                float g2 = wrow[128 + lane];
                float g3 = wrow[192 + lane];
                float g4 = wrow[256 + lane];
                #pragma unroll
                for (int j = 0; j < EB; ++j) {
                    float hk = hh[j][kk];
                    w00[j]  += hk * g0;
                    w01[j]  += hk * g1;
                    w10[j]  += hk * g2;
                    w11d[j] += hk * g3;
                    w11c[j] += hk * g4;
                }
            }
        }

        // ---- messages + scatter (lane = channel d) ----
        #pragma unroll
        for (int j = 0; j < EB; ++j) {
            if (!val[j]) continue;   // uniform across wave
            const float* us = u + (size_t)sidx[j] * 256;
            float m0  = us[lane];
            float m1x = us[64 + lane], m1y = us[128 + lane], m1z = us[192 + lane];

            float dotv = m1x * Yx[j] + m1y * Yy[j] + m1z * Yz[j];
            float cx = m1y * Yz[j] - m1z * Yy[j];
            float cy = m1z * Yx[j] - m1x * Yz[j];
            float cz = m1x * Yy[j] - m1y * Yx[j];

            float wm = w01[j] * m0;
            float* ar = acc + (size_t)ridx[j] * 256;
            atomicAdd(&ar[lane],        w00[j] * m0 + w11d[j] * dotv);
            atomicAdd(&ar[64 + lane],   wm * Yx[j] + w10[j] * m1x + w11c[j] * cx);
            atomicAdd(&ar[128 + lane],  wm * Yy[j] + w10[j] * m1y + w11c[j] * cy);
            atomicAdd(&ar[192 + lane],  wm * Yz[j] + w10[j] * m1z + w11c[j] * cz);
        }
    }
}

// ---------------------------------------------------------------------------
// Node epilogue: f0 = 0.25*a0@Wd0 + x0@Ws0[sp]; f1 = 0.25*a1@Wd1 + x1@Ws1[sp]
// ---------------------------------------------------------------------------
__global__ __launch_bounds__(256) void node_out_kernel(
    const float* __restrict__ acc, const float* __restrict__ node_feats,
    const int* __restrict__ node_specie,
    const float* __restrict__ Wd0, const float* __restrict__ Wd1,
    const float* __restrict__ Ws0, const float* __restrict__ Ws1,
    float* __restrict__ out)
{
    int n = blockIdx.x;
    int t = threadIdx.x;
    __shared__ float gates[64];
    int sp = node_specie[n];
    const float* accn = acc + (size_t)n * 256;
    const float* nf = node_feats + (size_t)n * 256;

    if (t < 128) {
        const float* ws0 = Ws0 + (size_t)sp * 64 * 128;
        float f = 0.f;
        #pragma unroll 8
        for (int c = 0; c < 64; ++c) {
            f += (0.25f * accn[c]) * Wd0[c * 128 + t];
            f += nf[c] * ws0[c * 128 + t];
        }
        float sv = f / (1.f + __expf(-f));
        if (t < 64) out[(size_t)n * 256 + t] = sv;   // scalars
        else        gates[t - 64] = sv;              // gates
    }
    __syncthreads();
    if (t < 192) {
        int i = t >> 6;       // component, uniform per wave
        int c2 = t & 63;
        const float* ws1 = Ws1 + (size_t)sp * 64 * 64;
        float f = 0.f;
        #pragma unroll 8
        for (int cc = 0; cc < 64; ++cc) {
            f += (0.25f * accn[64 + i * 64 + cc]) * Wd1[cc * 64 + c2];
            f += nf[64 + cc * 3 + i] * ws1[cc * 64 + c2];
        }
        out[(size_t)n * 256 + 64 + c2 * 3 + i] = f * gates[c2];
    }
}

// ---------------------------------------------------------------------------
extern "C" void kernel_launch(void* const* d_in, const int* in_sizes, int n_in,
                              void* d_out, int out_size, void* d_ws, size_t ws_size,
                              hipStream_t stream) {
    const float* vectors     = (const float*)d_in[0];
    const float* node_feats  = (const float*)d_in[1];
    const int*   node_specie = (const int*)d_in[2];
    const int*   senders     = (const int*)d_in[3];
    const int*   receivers   = (const int*)d_in[4];
    const float* W0_up       = (const float*)d_in[5];
    const float* W1_up       = (const float*)d_in[6];
    const float* Wm1         = (const float*)d_in[7];
    const float* Wm2         = (const float*)d_in[8];
    const float* Wm3         = (const float*)d_in[9];
    const float* Ws0         = (const float*)d_in[10];
    const float* Ws1         = (const float*)d_in[11];
    const float* Wd0         = (const float*)d_in[12];
    const float* Wd1         = (const float*)d_in[13];
    float* out = (float*)d_out;

    int E = in_sizes[0] / 3;
    int N = in_sizes[1] / 256;

    float* u   = (float*)d_ws;                 // N*256
    float* acc = u + (size_t)N * 256;          // N*256

    hipMemsetAsync(acc, 0, (size_t)N * 256 * sizeof(float), stream);

    node_up_kernel<<<N, 256, 0, stream>>>(node_feats, W0_up, W1_up, u);
    edge_kernel<<<2048, 256, 0, stream>>>(
        vectors, senders, receivers, u, Wm1, Wm2, Wm3, acc, E);
    node_out_kernel<<<N, 256, 0, stream>>>(
        acc, node_feats, node_specie, Wd0, Wd1, Ws0, Ws1, out);
}

// Round 3
// 967.278 us; speedup vs baseline: 4.4494x; 1.0557x over previous
//
#include <hip/hip_runtime.h>
#include <hip/hip_bf16.h>

#define EB 4   // edges per wave iteration

__device__ __forceinline__ unsigned bf16_rne(float x) {
    unsigned u = __float_as_uint(x);
    return (u + 0x7fffu + ((u >> 16) & 1u)) >> 16;
}

// ---------------------------------------------------------------------------
// Prep: pack Wm3 (64x320 f32) into bf16 pairs along k.
// Wm3P[(kk*5 + p)*64 + d] = bf16(Wm3[2kk][p*64+d]) | bf16(Wm3[2kk+1][p*64+d])<<16
// so a wave (lane=d) reads 256B coalesced per (kk,p).
// ---------------------------------------------------------------------------
__global__ __launch_bounds__(256) void prep_kernel(
    const float* __restrict__ Wm3, unsigned* __restrict__ Wm3P)
{
    int idx = blockIdx.x * 256 + threadIdx.x;   // 32*5*64 = 10240
    if (idx >= 10240) return;
    int d  = idx & 63;
    int p  = (idx >> 6) % 5;
    int kk = idx / 320;
    unsigned lo = bf16_rne(Wm3[(size_t)(2 * kk)     * 320 + p * 64 + d]);
    unsigned hi = bf16_rne(Wm3[(size_t)(2 * kk + 1) * 320 + p * 64 + d]);
    Wm3P[idx] = lo | (hi << 16);
}

// ---------------------------------------------------------------------------
// CSR build: histogram -> exclusive scan -> bucket fill
// ---------------------------------------------------------------------------
__global__ __launch_bounds__(256) void hist_kernel(
    const int* __restrict__ receivers, int* __restrict__ cnt, int E)
{
    int i = blockIdx.x * 256 + threadIdx.x;
    int stride = gridDim.x * 256;
    for (; i < E; i += stride) atomicAdd(&cnt[receivers[i]], 1);
}

__global__ __launch_bounds__(1024) void scan_kernel(
    const int* __restrict__ cnt, int* __restrict__ offs,
    int* __restrict__ cursor, int N)
{
    __shared__ int a[1024], b[1024];
    int t = threadIdx.x;
    int carry = 0;
    for (int base = 0; base < N; base += 1024) {
        int v = (base + t < N) ? cnt[base + t] : 0;
        a[t] = v;
        __syncthreads();
        int* src = a; int* dst = b;
        for (int off = 1; off < 1024; off <<= 1) {
            dst[t] = src[t] + ((t >= off) ? src[t - off] : 0);
            __syncthreads();
            int* tmp = src; src = dst; dst = tmp;
        }
        int incl = src[t];
        int tot  = src[1023];
        __syncthreads();
        if (base + t < N) {
            int e = carry + incl - v;
            offs[base + t] = e;
            cursor[base + t] = e;
        }
        carry += tot;
    }
    if (t == 0) offs[N] = carry;
}

__global__ __launch_bounds__(256) void fill_kernel(
    const int* __restrict__ receivers, int* __restrict__ cursor,
    int* __restrict__ eidx, int E)
{
    int i = blockIdx.x * 256 + threadIdx.x;
    int stride = gridDim.x * 256;
    for (; i < E; i += stride) {
        int pos = atomicAdd(&cursor[receivers[i]], 1);
        eidx[pos] = i;
    }
}

// ---------------------------------------------------------------------------
// Node up-projection: u[n] = [u0(64) | u1x(64) | u1y(64) | u1z(64)]
// ---------------------------------------------------------------------------
__global__ __launch_bounds__(256) void node_up_kernel(
    const float* __restrict__ node_feats, const float* __restrict__ W0_up,
    const float* __restrict__ W1_up, float* __restrict__ u)
{
    int n = blockIdx.x;
    int t = threadIdx.x;
    const float* nf = node_feats + (size_t)n * 256;
    float f = 0.f;
    if (t < 64) {
        #pragma unroll 8
        for (int c = 0; c < 64; ++c) f += nf[c] * W0_up[c * 64 + t];
        u[(size_t)n * 256 + t] = f;
    } else {
        int i = (t - 64) >> 6;
        int d = t & 63;
        #pragma unroll 8
        for (int c = 0; c < 64; ++c) f += nf[64 + c * 3 + i] * W1_up[c * 64 + d];
        u[(size_t)n * 256 + 64 + i * 64 + d] = f;
    }
}

// ---------------------------------------------------------------------------
// Edge kernel v3: one WAVE per RECEIVER NODE (CSR). lane = channel.
// Messages accumulated in registers, single coalesced store. No atomics.
// ---------------------------------------------------------------------------
__global__ __launch_bounds__(256, 2) void edge_kernel(
    const float* __restrict__ vectors, const int* __restrict__ senders,
    const int* __restrict__ eidx, const int* __restrict__ offs,
    const float* __restrict__ u,
    const float* __restrict__ Wm1, const float* __restrict__ Wm2,
    const unsigned* __restrict__ Wm3P, float* __restrict__ acc, int N)
{
    __shared__ float ldsH1[4][EB][64];
    __shared__ float ldsH2[4][EB][64];

    const int lane = threadIdx.x & 63;
    const int wv   = threadIdx.x >> 6;
    const int n    = blockIdx.x * 4 + wv;
    if (n >= N) return;

    // hoisted per-lane weight columns
    float wm1c[8], wm2c[64];
    #pragma unroll
    for (int b = 0; b < 8; ++b) wm1c[b] = Wm1[b * 64 + lane];
    #pragma unroll
    for (int k = 0; k < 64; ++k) wm2c[k] = Wm2[k * 64 + lane];

    const int beg = offs[n], end = offs[n + 1];

    float a0 = 0.f, a1x = 0.f, a1y = 0.f, a1z = 0.f;

    for (int p0 = beg; p0 < end; p0 += EB) {
        const int m = end - p0;   // >=1

        float Yx[EB], Yy[EB], Yz[EB];
        int   sidx[EB];
        bool  val[EB];

        // ---- layer 1: basis -> h1 (lane = hidden channel) ----
        #pragma unroll
        for (int j = 0; j < EB; ++j) {
            bool v = (j < m);
            const int e = v ? eidx[p0 + j] : eidx[p0];
            float vx = vectors[3 * (size_t)e + 0];
            float vy = vectors[3 * (size_t)e + 1];
            float vz = vectors[3 * (size_t)e + 2];
            float r = sqrtf(vx * vx + vy * vy + vz * vz);
            v = v && (r != 0.0f);
            float ir = (r != 0.0f) ? 1.0f / r : 0.0f;
            Yx[j] = vx * ir; Yy[j] = vy * ir; Yz[j] = vz * ir;
            sidx[j] = senders[e];
            val[j] = v;

            float ang = r * 0.6283185307179586f;   // pi/5
            float a = 0.f;
            #pragma unroll
            for (int b = 0; b < 8; ++b) {
                float bs = 0.6324555320336759f * __sinf((float)(b + 1) * ang) * ir;
                a += bs * wm1c[b];
            }
            ldsH1[wv][j][lane] = a / (1.f + __expf(-a));
        }

        // ---- layer 2 ----
        float h2a[EB];
        #pragma unroll
        for (int j = 0; j < EB; ++j) h2a[j] = 0.f;
        #pragma unroll
        for (int k = 0; k < 64; k += 4) {
            float hh[EB][4];
            #pragma unroll
            for (int j = 0; j < EB; ++j) {
                float4 t = *(const float4*)&ldsH1[wv][j][k];
                hh[j][0] = t.x; hh[j][1] = t.y; hh[j][2] = t.z; hh[j][3] = t.w;
            }
            #pragma unroll
            for (int kk = 0; kk < 4; ++kk)
                #pragma unroll
                for (int j = 0; j < EB; ++j)
                    h2a[j] += hh[j][kk] * wm2c[k + kk];
        }
        #pragma unroll
        for (int j = 0; j < EB; ++j)
            ldsH2[wv][j][lane] = h2a[j] / (1.f + __expf(-h2a[j]));

        // ---- layer 3: bf16-packed Wm3, coalesced; wmix[p*64+lane] ----
        float w00[EB], w01[EB], w10[EB], w11d[EB], w11c[EB];
        #pragma unroll
        for (int j = 0; j < EB; ++j) {
            w00[j] = 0.f; w01[j] = 0.f; w10[j] = 0.f; w11d[j] = 0.f; w11c[j] = 0.f;
        }
        #pragma unroll 4
        for (int kq = 0; kq < 16; ++kq) {       // 4 k's per iter
            float hh[EB][4];
            #pragma unroll
            for (int j = 0; j < EB; ++j) {
                float4 t = *(const float4*)&ldsH2[wv][j][kq * 4];
                hh[j][0] = t.x; hh[j][1] = t.y; hh[j][2] = t.z; hh[j][3] = t.w;
            }
            #pragma unroll
            for (int half = 0; half < 2; ++half) {
                const int kk = kq * 2 + half;    // dword covers k=2kk,2kk+1
                const unsigned* wrow = Wm3P + (size_t)kk * 5 * 64 + lane;
                unsigned q0 = wrow[0];
                unsigned q1 = wrow[64];
                unsigned q2 = wrow[128];
                unsigned q3 = wrow[192];
                unsigned q4 = wrow[256];
                float g0a = __uint_as_float(q0 << 16), g0b = __uint_as_float(q0 & 0xffff0000u);
                float g1a = __uint_as_float(q1 << 16), g1b = __uint_as_float(q1 & 0xffff0000u);
                float g2a = __uint_as_float(q2 << 16), g2b = __uint_as_float(q2 & 0xffff0000u);
                float g3a = __uint_as_float(q3 << 16), g3b = __uint_as_float(q3 & 0xffff0000u);
                float g4a = __uint_as_float(q4 << 16), g4b = __uint_as_float(q4 & 0xffff0000u);
                #pragma unroll
                for (int j = 0; j < EB; ++j) {
                    float ha = hh[j][half * 2 + 0];
                    float hb = hh[j][half * 2 + 1];
                    w00[j]  += ha * g0a + hb * g0b;
                    w01[j]  += ha * g1a + hb * g1b;
                    w10[j]  += ha * g2a + hb * g2b;
                    w11d[j] += ha * g3a + hb * g3b;
                    w11c[j] += ha * g4a + hb * g4b;
                }
            }
        }

        // ---- messages: accumulate in registers ----
        #pragma unroll
        for (int j = 0; j < EB; ++j) {
            if (!val[j]) continue;   // wave-uniform
            const float* us = u + (size_t)sidx[j] * 256;
            float m0  = us[lane];
            float m1x = us[64 + lane], m1y = us[128 + lane], m1z = us[192 + lane];

            float dotv = m1x * Yx[j] + m1y * Yy[j] + m1z * Yz[j];
            float cx = m1y * Yz[j] - m1z * Yy[j];
            float cy = m1z * Yx[j] - m1x * Yz[j];
            float cz = m1x * Yy[j] - m1y * Yx[j];

            float wm = w01[j] * m0;
            a0  += w00[j] * m0 + w11d[j] * dotv;
            a1x += wm * Yx[j] + w10[j] * m1x + w11c[j] * cx;
            a1y += wm * Yy[j] + w10[j] * m1y + w11c[j] * cy;
            a1z += wm * Yz[j] + w10[j] * m1z + w11c[j] * cz;
        }
    }

    float* ar = acc + (size_t)n * 256;
    ar[lane]       = a0;
    ar[64 + lane]  = a1x;
    ar[128 + lane] = a1y;
    ar[192 + lane] = a1z;
}

// ---------------------------------------------------------------------------
// Node epilogue
// ---------------------------------------------------------------------------
__global__ __launch_bounds__(256) void node_out_kernel(
    const float* __restrict__ acc, const float* __restrict__ node_feats,
    const int* __restrict__ node_specie,
    const float* __restrict__ Wd0, const float* __restrict__ Wd1,
    const float* __restrict__ Ws0, const float* __restrict__ Ws1,
    float* __restrict__ out)
{
    int n = blockIdx.x;
    int t = threadIdx.x;
    __shared__ float gates[64];
    int sp = node_specie[n];
    const float* accn = acc + (size_t)n * 256;
    const float* nf = node_feats + (size_t)n * 256;

    if (t < 128) {
        const float* ws0 = Ws0 + (size_t)sp * 64 * 128;
        float f = 0.f;
        #pragma unroll 8
        for (int c = 0; c < 64; ++c) {
            f += (0.25f * accn[c]) * Wd0[c * 128 + t];
            f += nf[c] * ws0[c * 128 + t];
        }
        float sv = f / (1.f + __expf(-f));
        if (t < 64) out[(size_t)n * 256 + t] = sv;
        else        gates[t - 64] = sv;
    }
    __syncthreads();
    if (t < 192) {
        int i = t >> 6;
        int c2 = t & 63;
        const float* ws1 = Ws1 + (size_t)sp * 64 * 64;
        float f = 0.f;
        #pragma unroll 8
        for (int cc = 0; cc < 64; ++cc) {
            f += (0.25f * accn[64 + i * 64 + cc]) * Wd1[cc * 64 + c2];
            f += nf[64 + cc * 3 + i] * ws1[cc * 64 + c2];
        }
        out[(size_t)n * 256 + 64 + c2 * 3 + i] = f * gates[c2];
    }
}

// ---------------------------------------------------------------------------
extern "C" void kernel_launch(void* const* d_in, const int* in_sizes, int n_in,
                              void* d_out, int out_size, void* d_ws, size_t ws_size,
                              hipStream_t stream) {
    const float* vectors     = (const float*)d_in[0];
    const float* node_feats  = (const float*)d_in[1];
    const int*   node_specie = (const int*)d_in[2];
    const int*   senders     = (const int*)d_in[3];
    const int*   receivers   = (const int*)d_in[4];
    const float* W0_up       = (const float*)d_in[5];
    const float* W1_up       = (const float*)d_in[6];
    const float* Wm1         = (const float*)d_in[7];
    const float* Wm2         = (const float*)d_in[8];
    const float* Wm3         = (const float*)d_in[9];
    const float* Ws0         = (const float*)d_in[10];
    const float* Ws1         = (const float*)d_in[11];
    const float* Wd0         = (const float*)d_in[12];
    const float* Wd1         = (const float*)d_in[13];
    float* out = (float*)d_out;

    int E = in_sizes[0] / 3;
    int N = in_sizes[1] / 256;

    float*    u      = (float*)d_ws;                       // N*256 f32
    float*    acc    = u + (size_t)N * 256;                // N*256 f32
    unsigned* Wm3P   = (unsigned*)(acc + (size_t)N * 256); // 10240 u32
    int*      cnt    = (int*)(Wm3P + 10240);               // N
    int*      offs   = cnt + N;                            // N+1
    int*      cursor = offs + N + 1;                       // N
    int*      eidx   = cursor + N;                         // E

    hipMemsetAsync(cnt, 0, (size_t)N * sizeof(int), stream);

    prep_kernel<<<40, 256, 0, stream>>>(Wm3, Wm3P);
    hist_kernel<<<1024, 256, 0, stream>>>(receivers, cnt, E);
    scan_kernel<<<1, 1024, 0, stream>>>(cnt, offs, cursor, N);
    fill_kernel<<<1024, 256, 0, stream>>>(receivers, cursor, eidx, E);
    node_up_kernel<<<N, 256, 0, stream>>>(node_feats, W0_up, W1_up, u);
    edge_kernel<<<(N + 3) / 4, 256, 0, stream>>>(
        vectors, senders, eidx, offs, u, Wm1, Wm2, Wm3P, acc, N);
    node_out_kernel<<<N, 256, 0, stream>>>(
        acc, node_feats, node_specie, Wd0, Wd1, Ws0, Ws1, out);
}

// Round 4
// 846.131 us; speedup vs baseline: 5.0864x; 1.1432x over previous
//
#include <hip/hip_runtime.h>
#include <hip/hip_bf16.h>

typedef __attribute__((ext_vector_type(8))) short short8;
typedef __attribute__((ext_vector_type(4))) float f32x4;

__device__ __forceinline__ short bf16s(float x) {
    unsigned u = __float_as_uint(x);
    return (short)((u + 0x7fffu + ((u >> 16) & 1u)) >> 16);
}

// ---------------------------------------------------------------------------
// Prep: pack Wm2 (64x64) and Wm3 (64x320) into MFMA B-fragment layout (bf16).
// Frag (t,kh): lane l holds B[k = kh*32 + (l>>4)*8 + i][col = 16t + (l&15)].
// ---------------------------------------------------------------------------
__global__ __launch_bounds__(256) void prep_kernel(
    const float* __restrict__ Wm2, const float* __restrict__ Wm3,
    short* __restrict__ Wm2B, short* __restrict__ W3B)
{
    int idx = blockIdx.x * 256 + threadIdx.x;   // 48 frags * 64 lanes
    if (idx >= 48 * 64) return;
    int l = idx & 63, f = idx >> 6;
    int g = l >> 4, c = l & 15;
    if (f < 8) {
        int t = f >> 1, kh = f & 1;
        short8 v;
        #pragma unroll
        for (int i = 0; i < 8; ++i)
            v[i] = bf16s(Wm2[(size_t)(kh * 32 + g * 8 + i) * 64 + t * 16 + c]);
        *(short8*)(Wm2B + (size_t)f * 512 + l * 8) = v;
    } else {
        int f3 = f - 8, t = f3 >> 1, kh = f3 & 1;
        short8 v;
        #pragma unroll
        for (int i = 0; i < 8; ++i)
            v[i] = bf16s(Wm3[(size_t)(kh * 32 + g * 8 + i) * 320 + t * 16 + c]);
        *(short8*)(W3B + (size_t)f3 * 512 + l * 8) = v;
    }
}

// ---------------------------------------------------------------------------
// CSR build: histogram -> exclusive scan -> bucket fill
// ---------------------------------------------------------------------------
__global__ __launch_bounds__(256) void hist_kernel(
    const int* __restrict__ receivers, int* __restrict__ cnt, int E)
{
    int i = blockIdx.x * 256 + threadIdx.x;
    int stride = gridDim.x * 256;
    for (; i < E; i += stride) atomicAdd(&cnt[receivers[i]], 1);
}

__global__ __launch_bounds__(1024) void scan_kernel(
    const int* __restrict__ cnt, int* __restrict__ offs,
    int* __restrict__ cursor, int N)
{
    __shared__ int a[1024], b[1024];
    int t = threadIdx.x;
    int carry = 0;
    for (int base = 0; base < N; base += 1024) {
        int v = (base + t < N) ? cnt[base + t] : 0;
        a[t] = v;
        __syncthreads();
        int* src = a; int* dst = b;
        for (int off = 1; off < 1024; off <<= 1) {
            dst[t] = src[t] + ((t >= off) ? src[t - off] : 0);
            __syncthreads();
            int* tmp = src; src = dst; dst = tmp;
        }
        int incl = src[t];
        int tot  = src[1023];
        __syncthreads();
        if (base + t < N) {
            int e = carry + incl - v;
            offs[base + t] = e;
            cursor[base + t] = e;
        }
        carry += tot;
    }
    if (t == 0) offs[N] = carry;
}

__global__ __launch_bounds__(256) void fill_kernel(
    const int* __restrict__ receivers, int* __restrict__ cursor,
    int* __restrict__ eidx, int E)
{
    int i = blockIdx.x * 256 + threadIdx.x;
    int stride = gridDim.x * 256;
    for (; i < E; i += stride) {
        int pos = atomicAdd(&cursor[receivers[i]], 1);
        eidx[pos] = i;
    }
}

// ---------------------------------------------------------------------------
// Node up-projection: u[n] = [u0(64) | u1x(64) | u1y(64) | u1z(64)]
// ---------------------------------------------------------------------------
__global__ __launch_bounds__(256) void node_up_kernel(
    const float* __restrict__ node_feats, const float* __restrict__ W0_up,
    const float* __restrict__ W1_up, float* __restrict__ u)
{
    int n = blockIdx.x;
    int t = threadIdx.x;
    const float* nf = node_feats + (size_t)n * 256;
    float f = 0.f;
    if (t < 64) {
        #pragma unroll 8
        for (int c = 0; c < 64; ++c) f += nf[c] * W0_up[c * 64 + t];
        u[(size_t)n * 256 + t] = f;
    } else {
        int i = (t - 64) >> 6;
        int d = t & 63;
        #pragma unroll 8
        for (int c = 0; c < 64; ++c) f += nf[64 + c * 3 + i] * W1_up[c * 64 + d];
        u[(size_t)n * 256 + 64 + i * 64 + d] = f;
    }
}

// ---------------------------------------------------------------------------
// Edge kernel v4: wave per receiver node; 16-edge chunks through MFMA.
//  layer1 VALU -> ldsH1 bf16 (swizzled) -> MFMA layer2 -> ldsH2 -> MFMA layer3
//  C-layout of layer3 tile t=4p+q puts path p / channels 16q+c in the
//  consuming lane: messages computed from accumulators, no redistribution.
//  All LDS per-wave: no barriers. No atomics.
// ---------------------------------------------------------------------------
__global__ __launch_bounds__(256) void edge_kernel(
    const float* __restrict__ vectors, const int* __restrict__ senders,
    const int* __restrict__ eidx, const int* __restrict__ offs,
    const float* __restrict__ u, const float* __restrict__ Wm1,
    const short* __restrict__ Wm2B, const short* __restrict__ W3B,
    float* __restrict__ acc, int N)
{
    __shared__ __align__(16) short ldsH1[4][1024];   // [wave][16e * 64ch] bf16 swz
    __shared__ __align__(16) short ldsH2[4][1024];
    __shared__ __align__(16) float ldsMeta[4][16][4]; // Y.xyz + sender

    const int lane = threadIdx.x & 63;
    const int wv   = threadIdx.x >> 6;
    const int n    = blockIdx.x * 4 + wv;
    if (n >= N) return;
    const int c = lane & 15, g = lane >> 4;

    float wm1c[8];
    #pragma unroll
    for (int b = 0; b < 8; ++b) wm1c[b] = Wm1[b * 64 + lane];

    float a0q[4]  = {0.f, 0.f, 0.f, 0.f};
    float a1xq[4] = {0.f, 0.f, 0.f, 0.f};
    float a1yq[4] = {0.f, 0.f, 0.f, 0.f};
    float a1zq[4] = {0.f, 0.f, 0.f, 0.f};

    const int beg = offs[n], end = offs[n + 1];

    for (int p0 = beg; p0 < end; p0 += 16) {
        const int m = end - p0;   // valid edges this chunk: min(m,16)

        // ---- edge phase: r, Y, basis (Chebyshev), h1 -> ldsH1 ----
        #pragma unroll 2
        for (int j = 0; j < 16; ++j) {
            if (j < m) {
                int e = eidx[p0 + j];
                float vx = vectors[3 * (size_t)e + 0];
                float vy = vectors[3 * (size_t)e + 1];
                float vz = vectors[3 * (size_t)e + 2];
                float r = sqrtf(vx * vx + vy * vy + vz * vz);
                float ir = (r != 0.f) ? 1.f / r : 0.f;
                int snd = senders[e];
                if (lane == 0) {
                    float4 mt = make_float4(vx * ir, vy * ir, vz * ir,
                                            __int_as_float(snd));
                    *(float4*)&ldsMeta[wv][j][0] = mt;
                }
                // sin((b+1)*ang) via Chebyshev recurrence
                float ang = r * 0.6283185307179586f;   // pi/5
                float s1, c1;
                __sincosf(ang, &s1, &c1);
                float tc = 2.f * c1;
                float sb = s1, sp = 0.f;
                float a = 0.f;
                #pragma unroll
                for (int b = 0; b < 8; ++b) {
                    a += sb * wm1c[b];
                    float nx = tc * sb - sp;
                    sp = sb; sb = nx;
                }
                a *= 0.6324555320336759f * ir;
                float h1 = a / (1.f + __expf(-a));
                ldsH1[wv][j * 64 + (lane ^ ((j & 7) << 3))] = bf16s(h1);
            } else {
                ldsH1[wv][j * 64 + (lane ^ ((j & 7) << 3))] = 0;
                if (lane == 0) {
                    *(float4*)&ldsMeta[wv][j][0] =
                        make_float4(0.f, 0.f, 0.f, __int_as_float(0));
                }
            }
        }

        // ---- A-fragments of h1 (row = edge = lane&15, k = 8g+i + 32kh) ----
        short8 h1f[2];
        #pragma unroll
        for (int kh = 0; kh < 2; ++kh)
            h1f[kh] = *(const short8*)&ldsH1[wv][c * 64 + ((kh * 32 + g * 8) ^ ((c & 7) << 3))];

        // ---- layer 2: 4 n-tiles, silu, repack to ldsH2 ----
        #pragma unroll
        for (int t = 0; t < 4; ++t) {
            f32x4 cacc = {0.f, 0.f, 0.f, 0.f};
            #pragma unroll
            for (int kh = 0; kh < 2; ++kh) {
                short8 bf = *(const short8*)(Wm2B + (size_t)(t * 2 + kh) * 512 + lane * 8);
                cacc = __builtin_amdgcn_mfma_f32_16x16x32_bf16(h1f[kh], bf, cacc, 0, 0, 0);
            }
            #pragma unroll
            for (int i = 0; i < 4; ++i) {
                float x = cacc[i];
                float h2 = x / (1.f + __expf(-x));
                int row = 4 * g + i;
                ldsH2[wv][row * 64 + ((16 * t + c) ^ ((row & 7) << 3))] = bf16s(h2);
            }
        }

        short8 h2f[2];
        #pragma unroll
        for (int kh = 0; kh < 2; ++kh)
            h2f[kh] = *(const short8*)&ldsH2[wv][c * 64 + ((kh * 32 + g * 8) ^ ((c & 7) << 3))];

        // ---- per-chunk edge meta for this lane's 4 edge-rows ----
        float Yx[4], Yy[4], Yz[4];
        int snd[4];
        #pragma unroll
        for (int i = 0; i < 4; ++i) {
            int row = 4 * g + i;
            Yx[i] = ldsMeta[wv][row][0];
            Yy[i] = ldsMeta[wv][row][1];
            Yz[i] = ldsMeta[wv][row][2];
            snd[i] = __float_as_int(ldsMeta[wv][row][3]);
        }

        // ---- layer 3 + fused messages ----
        #pragma unroll
        for (int q = 0; q < 4; ++q) {
            const int d = 16 * q + c;
            float m0[4], m1x[4], m1y[4], m1z[4];
            #pragma unroll
            for (int i = 0; i < 4; ++i) {
                const float* us = u + (size_t)snd[i] * 256 + d;
                m0[i]  = us[0];
                m1x[i] = us[64];
                m1y[i] = us[128];
                m1z[i] = us[192];
            }
            float dotv[4], cx[4], cy[4], cz[4], mYx[4], mYy[4], mYz[4];
            #pragma unroll
            for (int i = 0; i < 4; ++i) {
                dotv[i] = m1x[i] * Yx[i] + m1y[i] * Yy[i] + m1z[i] * Yz[i];
                cx[i] = m1y[i] * Yz[i] - m1z[i] * Yy[i];
                cy[i] = m1z[i] * Yx[i] - m1x[i] * Yz[i];
                cz[i] = m1x[i] * Yy[i] - m1y[i] * Yx[i];
                mYx[i] = m0[i] * Yx[i];
                mYy[i] = m0[i] * Yy[i];
                mYz[i] = m0[i] * Yz[i];
            }
            #pragma unroll
            for (int p = 0; p < 5; ++p) {
                const int t = 4 * p + q;        // tile -> path p, group q
                f32x4 w = {0.f, 0.f, 0.f, 0.f};
                #pragma unroll
                for (int kh = 0; kh < 2; ++kh) {
                    short8 bf = *(const short8*)(W3B + (size_t)(t * 2 + kh) * 512 + lane * 8);
                    w = __builtin_amdgcn_mfma_f32_16x16x32_bf16(h2f[kh], bf, w, 0, 0, 0);
                }
                #pragma unroll
                for (int i = 0; i < 4; ++i) {
                    float wv_ = w[i];           // wmix[edge 4g+i][p*64+d]
                    if (p == 0) {
                        a0q[q] += wv_ * m0[i];
                    } else if (p == 1) {
                        a1xq[q] += wv_ * mYx[i];
                        a1yq[q] += wv_ * mYy[i];
                        a1zq[q] += wv_ * mYz[i];
                    } else if (p == 2) {
                        a1xq[q] += wv_ * m1x[i];
                        a1yq[q] += wv_ * m1y[i];
                        a1zq[q] += wv_ * m1z[i];
                    } else if (p == 3) {
                        a0q[q] += wv_ * dotv[i];
                    } else {
                        a1xq[q] += wv_ * cx[i];
                        a1yq[q] += wv_ * cy[i];
                        a1zq[q] += wv_ * cz[i];
                    }
                }
            }
        }
    }

    // ---- reduce partial sums across the 4 g-groups and store ----
    #pragma unroll
    for (int q = 0; q < 4; ++q) {
        a0q[q]  += __shfl_xor(a0q[q], 16);  a0q[q]  += __shfl_xor(a0q[q], 32);
        a1xq[q] += __shfl_xor(a1xq[q], 16); a1xq[q] += __shfl_xor(a1xq[q], 32);
        a1yq[q] += __shfl_xor(a1yq[q], 16); a1yq[q] += __shfl_xor(a1yq[q], 32);
        a1zq[q] += __shfl_xor(a1zq[q], 16); a1zq[q] += __shfl_xor(a1zq[q], 32);
    }
    if (lane < 16) {
        float* ar = acc + (size_t)n * 256;
        #pragma unroll
        for (int q = 0; q < 4; ++q) {
            ar[16 * q + lane]       = a0q[q];
            ar[64 + 16 * q + lane]  = a1xq[q];
            ar[128 + 16 * q + lane] = a1yq[q];
            ar[192 + 16 * q + lane] = a1zq[q];
        }
    }
}

// ---------------------------------------------------------------------------
// Node epilogue
// ---------------------------------------------------------------------------
__global__ __launch_bounds__(256) void node_out_kernel(
    const float* __restrict__ acc, const float* __restrict__ node_feats,
    const int* __restrict__ node_specie,
    const float* __restrict__ Wd0, const float* __restrict__ Wd1,
    const float* __restrict__ Ws0, const float* __restrict__ Ws1,
    float* __restrict__ out)
{
    int n = blockIdx.x;
    int t = threadIdx.x;
    __shared__ float gates[64];
    int sp = node_specie[n];
    const float* accn = acc + (size_t)n * 256;
    const float* nf = node_feats + (size_t)n * 256;

    if (t < 128) {
        const float* ws0 = Ws0 + (size_t)sp * 64 * 128;
        float f = 0.f;
        #pragma unroll 8
        for (int c = 0; c < 64; ++c) {
            f += (0.25f * accn[c]) * Wd0[c * 128 + t];
            f += nf[c] * ws0[c * 128 + t];
        }
        float sv = f / (1.f + __expf(-f));
        if (t < 64) out[(size_t)n * 256 + t] = sv;
        else        gates[t - 64] = sv;
    }
    __syncthreads();
    if (t < 192) {
        int i = t >> 6;
        int c2 = t & 63;
        const float* ws1 = Ws1 + (size_t)sp * 64 * 64;
        float f = 0.f;
        #pragma unroll 8
        for (int cc = 0; cc < 64; ++cc) {
            f += (0.25f * accn[64 + i * 64 + cc]) * Wd1[cc * 64 + c2];
            f += nf[64 + cc * 3 + i] * ws1[cc * 64 + c2];
        }
        out[(size_t)n * 256 + 64 + c2 * 3 + i] = f * gates[c2];
    }
}

// ---------------------------------------------------------------------------
extern "C" void kernel_launch(void* const* d_in, const int* in_sizes, int n_in,
                              void* d_out, int out_size, void* d_ws, size_t ws_size,
                              hipStream_t stream) {
    const float* vectors     = (const float*)d_in[0];
    const float* node_feats  = (const float*)d_in[1];
    const int*   node_specie = (const int*)d_in[2];
    const int*   senders     = (const int*)d_in[3];
    const int*   receivers   = (const int*)d_in[4];
    const float* W0_up       = (const float*)d_in[5];
    const float* W1_up       = (const float*)d_in[6];
    const float* Wm1         = (const float*)d_in[7];
    const float* Wm2         = (const float*)d_in[8];
    const float* Wm3         = (const float*)d_in[9];
    const float* Ws0         = (const float*)d_in[10];
    const float* Ws1         = (const float*)d_in[11];
    const float* Wd0         = (const float*)d_in[12];
    const float* Wd1         = (const float*)d_in[13];
    float* out = (float*)d_out;

    int E = in_sizes[0] / 3;
    int N = in_sizes[1] / 256;

    float* u    = (float*)d_ws;                      // N*256 f32
    float* acc  = u + (size_t)N * 256;               // N*256 f32
    short* Wm2B = (short*)(acc + (size_t)N * 256);   // 8*512 bf16
    short* W3B  = Wm2B + 8 * 512;                    // 40*512 bf16
    int*   cnt    = (int*)(W3B + 40 * 512);          // N
    int*   offs   = cnt + N;                         // N+1
    int*   cursor = offs + N + 1;                    // N
    int*   eidx   = cursor + N;                      // E

    hipMemsetAsync(cnt, 0, (size_t)N * sizeof(int), stream);

    prep_kernel<<<12, 256, 0, stream>>>(Wm2, Wm3, Wm2B, W3B);
    hist_kernel<<<1024, 256, 0, stream>>>(receivers, cnt, E);
    scan_kernel<<<1, 1024, 0, stream>>>(cnt, offs, cursor, N);
    fill_kernel<<<1024, 256, 0, stream>>>(receivers, cursor, eidx, E);
    node_up_kernel<<<N, 256, 0, stream>>>(node_feats, W0_up, W1_up, u);
    edge_kernel<<<(N + 3) / 4, 256, 0, stream>>>(
        vectors, senders, eidx, offs, u, Wm1, Wm2B, W3B, acc, N);
    node_out_kernel<<<N, 256, 0, stream>>>(
        acc, node_feats, node_specie, Wd0, Wd1, Ws0, Ws1, out);
}